// Round 3
// baseline (713.902 us; speedup 1.0000x reference)
//
#include <hip/hip_runtime.h>
#include <hip/hip_bf16.h>
#include <stdint.h>

typedef __attribute__((ext_vector_type(8))) short short8;
typedef __attribute__((ext_vector_type(4))) float floatx4;
typedef unsigned short u16;

#define MFMA(a,b,c) __builtin_amdgcn_mfma_f32_16x16x32_bf16(a,b,c,0,0,0)

__device__ __forceinline__ u16 f2bf(float f) {
  __hip_bfloat16 h = __float2bfloat16(f);
  return *reinterpret_cast<u16*>(&h);
}
__device__ __forceinline__ float bf2f(u16 u) {
  union { uint32_t i; float f; } v; v.i = ((uint32_t)u) << 16; return v.f;
}

__device__ __forceinline__ void gload16(const void* g, void* l) {
  __builtin_amdgcn_global_load_lds(
      (__attribute__((address_space(1))) void*)(uintptr_t)g,
      (__attribute__((address_space(3))) void*)l, 16, 0, 0);
}

// ---- convert + mask: xm[(b,l)][d] bf16, zeroed where masks[b,l] ----
__global__ void k_maskcvt(const float* __restrict__ x, const int* __restrict__ masks,
                          u16* __restrict__ xm) {
  int gid = blockIdx.x * blockDim.x + threadIdx.x;   // one per 8 elems
  size_t i8 = (size_t)gid * 8;
  int row = gid >> 7;                                // i8 / 1024
  int msk = masks[row];
  float4 v0 = make_float4(0.f,0.f,0.f,0.f), v1 = v0;
  if (!msk) {
    v0 = *(const float4*)(x + i8);
    v1 = *(const float4*)(x + i8 + 4);
  }
  ushort4 p0 = make_ushort4(f2bf(v0.x), f2bf(v0.y), f2bf(v0.z), f2bf(v0.w));
  ushort4 p1 = make_ushort4(f2bf(v1.x), f2bf(v1.y), f2bf(v1.z), f2bf(v1.w));
  *(ushort4*)(xm + i8) = p0;
  *(ushort4*)(xm + i8 + 4) = p1;
}

__global__ void k_cvt(const float* __restrict__ s, u16* __restrict__ d) {
  int gid = blockIdx.x * blockDim.x + threadIdx.x;
  size_t i8 = (size_t)gid * 8;
  float4 v0 = *(const float4*)(s + i8);
  float4 v1 = *(const float4*)(s + i8 + 4);
  ushort4 p0 = make_ushort4(f2bf(v0.x), f2bf(v0.y), f2bf(v0.z), f2bf(v0.w));
  ushort4 p1 = make_ushort4(f2bf(v1.x), f2bf(v1.y), f2bf(v1.z), f2bf(v1.w));
  *(ushort4*)(d + i8) = p0;
  *(ushort4*)(d + i8 + 4) = p1;
}

// ---- BT-GEMM 128x128xBK32, 4 waves, global_load_lds staging ----
// MODE 0: A=w_qkv_bf16 (3072x1024), B=xm (32768x1024): routes q_t / k / v
// MODE 1: A=att (32768x1024), B=w_out_bf16 (1024x1024): out fp32 + bias
template<int MODE>
__global__ __launch_bounds__(256) void gemm_bt(
    const u16* __restrict__ A, const u16* __restrict__ Bm, int K,
    u16* __restrict__ qt, u16* __restrict__ kbf, u16* __restrict__ vv,
    float* __restrict__ outp, const float* __restrict__ bias) {
  __shared__ u16 As[128*32];
  __shared__ u16 Bs[128*32];
  const int tid = threadIdx.x;
  const int lane = tid & 63, w = tid >> 6;
  const int wr = w >> 1, wc = w & 1;
  const int lrow = lane & 15, lk = lane >> 4;
  const int m0 = blockIdx.y * 128, n0 = blockIdx.x * 128;

  floatx4 acc[4][4] = {};

  for (int k0 = 0; k0 < K; k0 += 32) {
    #pragma unroll
    for (int r = 0; r < 2; ++r) {
      int li = r*256 + tid;
      int row = li >> 2, seg = li & 3;
      gload16(A  + (size_t)(m0 + row)*K + k0 + seg*8, (char*)As + (r*256 + w*64)*16);
      gload16(Bm + (size_t)(n0 + row)*K + k0 + seg*8, (char*)Bs + (r*256 + w*64)*16);
    }
    __syncthreads();
    short8 af[4], bff[4];
    #pragma unroll
    for (int m=0;m<4;m++) af[m]  = *(const short8*)&As[(wr*64 + m*16 + lrow)*32 + lk*8];
    #pragma unroll
    for (int n=0;n<4;n++) bff[n] = *(const short8*)&Bs[(wc*64 + n*16 + lrow)*32 + lk*8];
    #pragma unroll
    for (int m=0;m<4;m++)
      #pragma unroll
      for (int n=0;n<4;n++)
        acc[m][n] = MFMA(af[m], bff[n], acc[m][n]);
    __syncthreads();
  }

  #pragma unroll
  for (int m=0;m<4;m++) {
    const int rbase = m0 + wr*64 + m*16;   // uniform per frag-row
    #pragma unroll
    for (int n=0;n<4;n++) {
      const int ocol = n0 + wc*64 + n*16 + lrow;
      floatx4 d = acc[m][n];
      if (MODE == 0) {
        const int b = ocol >> 12, l = ocol & 4095;
        if (rbase < 1024) {            // q -> q_t[(b,l)][o], scaled
          int orow = rbase + lk*4;
          ushort4 p = make_ushort4(f2bf(d[0]*0.125f), f2bf(d[1]*0.125f),
                                   f2bf(d[2]*0.125f), f2bf(d[3]*0.125f));
          *(ushort4*)(qt + (size_t)ocol*1024 + orow) = p;
        } else if (rbase < 2048) {     // k -> kbf[b][row][l]
          int orow = rbase - 1024 + lk*4;
          #pragma unroll
          for (int r=0;r<4;r++)
            kbf[((size_t)b*1024 + orow + r)*4096 + l] = f2bf(d[r]);
        } else {                       // v -> vv[b][row][l]
          int orow = rbase - 2048 + lk*4;
          #pragma unroll
          for (int r=0;r<4;r++)
            vv[((size_t)b*1024 + orow + r)*4096 + l] = f2bf(d[r]);
        }
      } else {                         // out[(b,l)][o] fp32 + bias
        int orow = rbase + lk*4;
        float bval = bias[ocol];
        #pragma unroll
        for (int r=0;r<4;r++)
          outp[(size_t)(orow + r)*1024 + ocol] = d[r] + bval;
      }
    }
  }
}

// ---- softmax over L per (b,row): kbf bf16 -> kbf bf16 IN-PLACE, masked -> 0 ----
__global__ __launch_bounds__(256) void k_softmax(u16* __restrict__ kbf,
    const int* __restrict__ masks) {
  const int row = blockIdx.x;            // 0..8191
  const int b = row >> 10;
  u16* src = kbf + (size_t)row * 4096;
  const int* mk = masks + (size_t)b * 4096;
  const int tid = threadIdx.x;
  const int lane = tid & 63, wv = tid >> 6;

  float v[16]; int mv[16];
  float mx = -INFINITY;
  #pragma unroll
  for (int i=0;i<4;i++) {
    int l = i*1024 + tid*4;
    ushort4 kv = *(const ushort4*)(src + l);
    int4 mm = *(const int4*)(mk + l);
    float f0=bf2f(kv.x), f1=bf2f(kv.y), f2=bf2f(kv.z), f3=bf2f(kv.w);
    v[i*4+0]=f0; v[i*4+1]=f1; v[i*4+2]=f2; v[i*4+3]=f3;
    mv[i*4+0]=mm.x; mv[i*4+1]=mm.y; mv[i*4+2]=mm.z; mv[i*4+3]=mm.w;
    if (!mm.x) mx = fmaxf(mx, f0);
    if (!mm.y) mx = fmaxf(mx, f1);
    if (!mm.z) mx = fmaxf(mx, f2);
    if (!mm.w) mx = fmaxf(mx, f3);
  }
  #pragma unroll
  for (int o=32;o;o>>=1) mx = fmaxf(mx, __shfl_xor(mx, o));
  __shared__ float sred[4];
  __shared__ float ssum[4];
  if (lane==0) sred[wv] = mx;
  __syncthreads();
  mx = fmaxf(fmaxf(sred[0],sred[1]), fmaxf(sred[2],sred[3]));

  float s = 0.f;
  #pragma unroll
  for (int i=0;i<16;i++) {
    float e = mv[i] ? 0.f : __expf(v[i]-mx);
    v[i] = e; s += e;
  }
  #pragma unroll
  for (int o=32;o;o>>=1) s += __shfl_xor(s, o);
  if (lane==0) ssum[wv] = s;
  __syncthreads();
  s = ssum[0]+ssum[1]+ssum[2]+ssum[3];
  float inv = 1.f/s;
  #pragma unroll
  for (int i=0;i<4;i++) {
    int l = i*1024 + tid*4;
    ushort4 p = make_ushort4(f2bf(v[i*4]*inv), f2bf(v[i*4+1]*inv),
                             f2bf(v[i*4+2]*inv), f2bf(v[i*4+3]*inv));
    *(ushort4*)(src + l) = p;
  }
}

// ---- context[bh][d][e] = sum_l ksm[bh*64+d][l] * vv[bh*64+e][l]; 4-wave K-split ----
__global__ __launch_bounds__(256) void k_context(const u16* __restrict__ ksm,
    const u16* __restrict__ vv, u16* __restrict__ ctx) {
  const int bh = blockIdx.x;             // 0..127
  const int tid = threadIdx.x, lane = tid&63, w = tid>>6;
  const int lrow = lane&15, lk = lane>>4;
  const u16* Kb = ksm + (size_t)bh*64*4096;
  const u16* Vb = vv  + (size_t)bh*64*4096;
  floatx4 acc[4][4] = {};
  const int kbeg = w*1024;
  for (int kk=0; kk<1024; kk+=32) {
    short8 af[4], bff[4];
    #pragma unroll
    for (int m=0;m<4;m++) af[m]  = *(const short8*)(Kb + (size_t)(m*16+lrow)*4096 + kbeg+kk + lk*8);
    #pragma unroll
    for (int n=0;n<4;n++) bff[n] = *(const short8*)(Vb + (size_t)(n*16+lrow)*4096 + kbeg+kk + lk*8);
    #pragma unroll
    for (int m=0;m<4;m++)
      #pragma unroll
      for (int n=0;n<4;n++)
        acc[m][n] = MFMA(af[m], bff[n], acc[m][n]);
  }
  __shared__ float red[4][4096];
  #pragma unroll
  for (int m=0;m<4;m++)
    #pragma unroll
    for (int n=0;n<4;n++)
      #pragma unroll
      for (int r=0;r<4;r++) {
        int dd = m*16 + lk*4 + r, ee = n*16 + lrow;
        red[w][dd*64+ee] = acc[m][n][r];
      }
  __syncthreads();
  u16* cb = ctx + (size_t)bh*4096;
  #pragma unroll
  for (int i=0;i<16;i++) {
    int idx = i*256 + tid;
    cb[idx] = f2bf(red[0][idx]+red[1][idx]+red[2][idx]+red[3][idx]);
  }
}

// ---- att[(b,l)][h*64+d] = sum_e qt[(b,l)][h*64+e] * ctx[bh][d][e] ----
__global__ __launch_bounds__(128) void k_att(const u16* __restrict__ qt,
    const u16* __restrict__ ctx, u16* __restrict__ att) {
  const int b = blockIdx.z, h = blockIdx.y;
  const int l0 = blockIdx.x * 128;
  const int tid = threadIdx.x, lane = tid&63, w = tid>>6;   // 2 waves
  const int lrow = lane&15, lk = lane>>4;
  const u16* Ab = qt + ((size_t)b*4096 + l0 + w*64)*1024 + h*64;
  const u16* Bb = ctx + (size_t)(b*16+h)*4096;
  floatx4 acc[4][4] = {};
  #pragma unroll
  for (int kk=0; kk<64; kk+=32) {
    short8 af[4], bff[4];
    #pragma unroll
    for (int m=0;m<4;m++) af[m]  = *(const short8*)(Ab + (size_t)(m*16+lrow)*1024 + kk + lk*8);
    #pragma unroll
    for (int n=0;n<4;n++) bff[n] = *(const short8*)(Bb + (n*16+lrow)*64 + kk + lk*8);
    #pragma unroll
    for (int m=0;m<4;m++)
      #pragma unroll
      for (int n=0;n<4;n++)
        acc[m][n] = MFMA(af[m], bff[n], acc[m][n]);
  }
  const size_t rowbase = (size_t)b*4096 + l0 + w*64;
  #pragma unroll
  for (int m=0;m<4;m++)
    #pragma unroll
    for (int n=0;n<4;n++)
      #pragma unroll
      for (int r=0;r<4;r++)
        att[(rowbase + m*16 + lk*4 + r)*1024 + h*64 + n*16 + lrow] = f2bf(acc[m][n][r]);
}

extern "C" void kernel_launch(void* const* d_in, const int* in_sizes, int n_in,
                              void* d_out, int out_size, void* d_ws, size_t ws_size,
                              hipStream_t stream) {
  const float* x     = (const float*)d_in[0];
  const int*   masks = (const int*)d_in[1];
  const float* w_qkv = (const float*)d_in[2];
  const float* w_out = (const float*)d_in[3];
  const float* b_out = (const float*)d_in[4];
  float* out = (float*)d_out;

  // Workspace layout (total ~141 MB):
  char* ws = (char*)d_ws;
  u16* xm  = (u16*)(ws);                    // 64 MB; reused as att after GEMM1
  u16* att = xm;
  u16* qt  = (u16*)(ws + (64ull<<20));      // 64 MB
  u16* wqb = (u16*)(ws + (128ull<<20));     // 6 MB
  u16* wob = (u16*)(ws + (136ull<<20));     // 2 MB
  u16* ctx = (u16*)(ws + (140ull<<20));     // 1 MB

  // k/v live inside d_out (128 MiB of the 134.2 MB fp32 output buffer);
  // both are dead before gemm_bt<1> overwrites d_out with the final result.
  // kbf = 8*1024*4096 u16 = 33,554,432 elements = 64 MiB.
  u16* kbf = (u16*)d_out;                   // [8][1024][4096] bf16
  u16* vv  = (u16*)d_out + 33554432ull;     // [8][1024][4096] bf16  (FIX: was +67M -> OOB)

  k_maskcvt<<<16384, 256, 0, stream>>>(x, masks, xm);            // 32768*1024
  k_cvt<<<1536, 256, 0, stream>>>(w_qkv, wqb);                   // 3072*1024
  k_cvt<<<512, 256, 0, stream>>>(w_out, wob);                    // 1024*1024

  gemm_bt<0><<<dim3(256,24), 256, 0, stream>>>(wqb, xm, 1024,
                                               qt, kbf, vv, nullptr, nullptr);
  k_softmax<<<8192, 256, 0, stream>>>(kbf, masks);
  k_context<<<128, 256, 0, stream>>>(kbf, vv, ctx);
  k_att<<<dim3(32,16,8), 128, 0, stream>>>(qt, ctx, att);
  gemm_bt<1><<<dim3(8,256), 256, 0, stream>>>(att, wob, 1024,
                                              nullptr, nullptr, nullptr, out, b_out);
}

// Round 4
// 567.366 us; speedup vs baseline: 1.2583x; 1.2583x over previous
//
#include <hip/hip_runtime.h>
#include <hip/hip_bf16.h>
#include <stdint.h>

typedef __attribute__((ext_vector_type(8))) short short8;
typedef __attribute__((ext_vector_type(4))) float floatx4;
typedef unsigned short u16;

#define MFMA(a,b,c) __builtin_amdgcn_mfma_f32_16x16x32_bf16(a,b,c,0,0,0)

__device__ __forceinline__ u16 f2bf(float f) {
  __hip_bfloat16 h = __float2bfloat16(f);
  return *reinterpret_cast<u16*>(&h);
}
__device__ __forceinline__ float bf2f(u16 u) {
  union { uint32_t i; float f; } v; v.i = ((uint32_t)u) << 16; return v.f;
}

__device__ __forceinline__ void gload16(const void* g, void* l) {
  __builtin_amdgcn_global_load_lds(
      (__attribute__((address_space(1))) void*)(uintptr_t)g,
      (__attribute__((address_space(3))) void*)l, 16, 0, 0);
}

// ---- convert + mask: xm[(b,l)][d] bf16, zeroed where masks[b,l] ----
__global__ void k_maskcvt(const float* __restrict__ x, const int* __restrict__ masks,
                          u16* __restrict__ xm) {
  int gid = blockIdx.x * blockDim.x + threadIdx.x;   // one per 8 elems
  size_t i8 = (size_t)gid * 8;
  int row = gid >> 7;                                // i8 / 1024
  int msk = masks[row];
  float4 v0 = make_float4(0.f,0.f,0.f,0.f), v1 = v0;
  if (!msk) {
    v0 = *(const float4*)(x + i8);
    v1 = *(const float4*)(x + i8 + 4);
  }
  ushort4 p0 = make_ushort4(f2bf(v0.x), f2bf(v0.y), f2bf(v0.z), f2bf(v0.w));
  ushort4 p1 = make_ushort4(f2bf(v1.x), f2bf(v1.y), f2bf(v1.z), f2bf(v1.w));
  *(ushort4*)(xm + i8) = p0;
  *(ushort4*)(xm + i8 + 4) = p1;
}

__global__ void k_cvt(const float* __restrict__ s, u16* __restrict__ d) {
  int gid = blockIdx.x * blockDim.x + threadIdx.x;
  size_t i8 = (size_t)gid * 8;
  float4 v0 = *(const float4*)(s + i8);
  float4 v1 = *(const float4*)(s + i8 + 4);
  ushort4 p0 = make_ushort4(f2bf(v0.x), f2bf(v0.y), f2bf(v0.z), f2bf(v0.w));
  ushort4 p1 = make_ushort4(f2bf(v1.x), f2bf(v1.y), f2bf(v1.z), f2bf(v1.w));
  *(ushort4*)(d + i8) = p0;
  *(ushort4*)(d + i8 + 4) = p1;
}

// ---- transpose+scale the q rows of w_qkv: wqT[c][e] = w_qkv[e][c] * 0.125 ----
__global__ __launch_bounds__(256) void k_cvtT(const float* __restrict__ src,
                                              u16* __restrict__ dst) {
  __shared__ float t[32][33];
  const int e0 = blockIdx.x * 32, c0 = blockIdx.y * 32;
  const int tx = threadIdx.x & 31, ty = threadIdx.x >> 5;   // ty in [0,8)
  #pragma unroll
  for (int i = 0; i < 4; i++)
    t[ty + i*8][tx] = src[(size_t)(e0 + ty + i*8) * 1024 + c0 + tx];
  __syncthreads();
  #pragma unroll
  for (int i = 0; i < 4; i++)
    dst[(size_t)(c0 + ty + i*8) * 1024 + e0 + tx] = f2bf(t[tx][ty + i*8] * 0.125f);
}

// ---- BT-GEMM 128x128xK1024, 4 waves, global_load_lds staging ----
// MODE 0: A=wkv (2048x1024), B=xm (32768x1024): routes k / v  (grid 4096 1D, XCD-swizzled)
// MODE 1: A=xm (32768x1024), B=mb[b] (1024x1024): out fp32 + bias (grid 2048 1D, XCD-swizzled)
// MODE 2: A=wout (1024x1024), B=vbT[b] (1024x1024): mb[b] bf16 (grid (64,1,8))
template<int MODE>
__global__ __launch_bounds__(256) void gemm_bt(
    const u16* __restrict__ A, const u16* __restrict__ Bm,
    u16* __restrict__ o_k, u16* __restrict__ o_v,
    u16* __restrict__ o_mb,
    float* __restrict__ outp, const float* __restrict__ bias) {
  constexpr int K = 1024;
  __shared__ u16 As[128*32];
  __shared__ u16 Bs[128*32];
  const int tid = threadIdx.x;
  const int lane = tid & 63, w = tid >> 6;
  const int wr = w >> 1, wc = w & 1;
  const int lrow = lane & 15, lk = lane >> 4;

  int m_idx, n_idx, zb = 0;
  if (MODE == 0) {        // each XCD owns 32 consecutive n-panels; m fast within
    int id = blockIdx.x, j = id >> 3;
    m_idx = j & 15; n_idx = (id & 7) * 32 + (j >> 4);
  } else if (MODE == 1) { // each XCD owns 32 consecutive m-panels; n fast within
    int id = blockIdx.x, j = id >> 3;
    n_idx = j & 7; m_idx = (id & 7) * 32 + (j >> 3);
  } else {
    m_idx = blockIdx.x & 7; n_idx = blockIdx.x >> 3; zb = blockIdx.z;
  }
  const int m0 = m_idx * 128, n0 = n_idx * 128;

  const u16* Ap = A + (size_t)m0 * K;
  const u16* Bp;
  if (MODE == 1)      Bp = Bm + (size_t)(m0 >> 12) * 1048576 + (size_t)n0 * K;
  else if (MODE == 2) Bp = Bm + (size_t)zb * 1048576 + (size_t)n0 * K;
  else                Bp = Bm + (size_t)n0 * K;

  floatx4 acc[4][4] = {};

  for (int k0 = 0; k0 < K; k0 += 32) {
    #pragma unroll
    for (int r = 0; r < 2; ++r) {
      int li = r*256 + tid;
      int row = li >> 2, seg = li & 3;
      gload16(Ap + (size_t)row * K + k0 + seg*8, (char*)As + (r*256 + w*64)*16);
      gload16(Bp + (size_t)row * K + k0 + seg*8, (char*)Bs + (r*256 + w*64)*16);
    }
    __syncthreads();
    short8 af[4], bff[4];
    #pragma unroll
    for (int m=0;m<4;m++) af[m]  = *(const short8*)&As[(wr*64 + m*16 + lrow)*32 + lk*8];
    #pragma unroll
    for (int n=0;n<4;n++) bff[n] = *(const short8*)&Bs[(wc*64 + n*16 + lrow)*32 + lk*8];
    #pragma unroll
    for (int m=0;m<4;m++)
      #pragma unroll
      for (int n=0;n<4;n++)
        acc[m][n] = MFMA(af[m], bff[n], acc[m][n]);
    __syncthreads();
  }

  #pragma unroll
  for (int m=0;m<4;m++) {
    const int rbase = m0 + wr*64 + m*16;   // uniform per frag-row
    #pragma unroll
    for (int n=0;n<4;n++) {
      const int ocol = n0 + wc*64 + n*16 + lrow;
      floatx4 d = acc[m][n];
      if (MODE == 0) {
        const int b = ocol >> 12, l = ocol & 4095;
        if (rbase < 1024) {            // k -> o_k[b][row][l]
          int orow = rbase + lk*4;
          #pragma unroll
          for (int r=0;r<4;r++)
            o_k[((size_t)b*1024 + orow + r)*4096 + l] = f2bf(d[r]);
        } else {                       // v -> o_v[b][row][l]
          int orow = rbase - 1024 + lk*4;
          #pragma unroll
          for (int r=0;r<4;r++)
            o_v[((size_t)b*1024 + orow + r)*4096 + l] = f2bf(d[r]);
        }
      } else if (MODE == 1) {          // out[(b,l)][o] fp32 + bias
        int orow = rbase + lk*4;
        float bval = bias[ocol];
        #pragma unroll
        for (int r=0;r<4;r++)
          outp[(size_t)(orow + r)*1024 + ocol] = d[r] + bval;
      } else {                         // mb[b][o][c] bf16
        int orow = rbase + lk*4;
        #pragma unroll
        for (int r=0;r<4;r++)
          o_mb[(size_t)zb*1048576 + (size_t)(orow + r)*1024 + ocol] = f2bf(d[r]);
      }
    }
  }
}

// ---- softmax over L per (b,row): kbf bf16 -> kbf bf16 IN-PLACE, masked -> 0 ----
__global__ __launch_bounds__(256) void k_softmax(u16* __restrict__ kbf,
    const int* __restrict__ masks) {
  const int row = blockIdx.x;            // 0..8191
  const int b = row >> 10;
  u16* src = kbf + (size_t)row * 4096;
  const int* mk = masks + (size_t)b * 4096;
  const int tid = threadIdx.x;
  const int lane = tid & 63, wv = tid >> 6;

  float v[16]; int mv[16];
  float mx = -INFINITY;
  #pragma unroll
  for (int i=0;i<4;i++) {
    int l = i*1024 + tid*4;
    ushort4 kv = *(const ushort4*)(src + l);
    int4 mm = *(const int4*)(mk + l);
    float f0=bf2f(kv.x), f1=bf2f(kv.y), f2=bf2f(kv.z), f3=bf2f(kv.w);
    v[i*4+0]=f0; v[i*4+1]=f1; v[i*4+2]=f2; v[i*4+3]=f3;
    mv[i*4+0]=mm.x; mv[i*4+1]=mm.y; mv[i*4+2]=mm.z; mv[i*4+3]=mm.w;
    if (!mm.x) mx = fmaxf(mx, f0);
    if (!mm.y) mx = fmaxf(mx, f1);
    if (!mm.z) mx = fmaxf(mx, f2);
    if (!mm.w) mx = fmaxf(mx, f3);
  }
  #pragma unroll
  for (int o=32;o;o>>=1) mx = fmaxf(mx, __shfl_xor(mx, o));
  __shared__ float sred[4];
  __shared__ float ssum[4];
  if (lane==0) sred[wv] = mx;
  __syncthreads();
  mx = fmaxf(fmaxf(sred[0],sred[1]), fmaxf(sred[2],sred[3]));

  float s = 0.f;
  #pragma unroll
  for (int i=0;i<16;i++) {
    float e = mv[i] ? 0.f : __expf(v[i]-mx);
    v[i] = e; s += e;
  }
  #pragma unroll
  for (int o=32;o;o>>=1) s += __shfl_xor(s, o);
  if (lane==0) ssum[wv] = s;
  __syncthreads();
  s = ssum[0]+ssum[1]+ssum[2]+ssum[3];
  float inv = 1.f/s;
  #pragma unroll
  for (int i=0;i<4;i++) {
    int l = i*1024 + tid*4;
    ushort4 p = make_ushort4(f2bf(v[i*4]*inv), f2bf(v[i*4+1]*inv),
                             f2bf(v[i*4+2]*inv), f2bf(v[i*4+3]*inv));
    *(ushort4*)(src + l) = p;
  }
}

// ---- context[bh][d][e] = sum_l ksm[bh*64+d][l] * vv[bh*64+e][l]; 4-wave K-split ----
__global__ __launch_bounds__(256) void k_context(const u16* __restrict__ ksm,
    const u16* __restrict__ vv, u16* __restrict__ ctx) {
  const int bh = blockIdx.x;             // 0..127
  const int tid = threadIdx.x, lane = tid&63, w = tid>>6;
  const int lrow = lane&15, lk = lane>>4;
  const u16* Kb = ksm + (size_t)bh*64*4096;
  const u16* Vb = vv  + (size_t)bh*64*4096;
  floatx4 acc[4][4] = {};
  const int kbeg = w*1024;
  for (int kk=0; kk<1024; kk+=32) {
    short8 af[4], bff[4];
    #pragma unroll
    for (int m=0;m<4;m++) af[m]  = *(const short8*)(Kb + (size_t)(m*16+lrow)*4096 + kbeg+kk + lk*8);
    #pragma unroll
    for (int n=0;n<4;n++) bff[n] = *(const short8*)(Vb + (size_t)(n*16+lrow)*4096 + kbeg+kk + lk*8);
    #pragma unroll
    for (int m=0;m<4;m++)
      #pragma unroll
      for (int n=0;n<4;n++)
        acc[m][n] = MFMA(af[m], bff[n], acc[m][n]);
  }
  __shared__ float red[4][4096];
  #pragma unroll
  for (int m=0;m<4;m++)
    #pragma unroll
    for (int n=0;n<4;n++)
      #pragma unroll
      for (int r=0;r<4;r++) {
        int dd = m*16 + lk*4 + r, ee = n*16 + lrow;
        red[w][dd*64+ee] = acc[m][n][r];
      }
  __syncthreads();
  u16* cb = ctx + (size_t)bh*4096;
  #pragma unroll
  for (int i=0;i<16;i++) {
    int idx = i*256 + tid;
    cb[idx] = f2bf(red[0][idx]+red[1][idx]+red[2][idx]+red[3][idx]);
  }
}

// ---- vbT[b][c][h*64+d] = sum_e ctx[b,h,d,e] * wqT[c][h*64+e] ----
__global__ __launch_bounds__(256) void k_vb(const u16* __restrict__ ctx,
    const u16* __restrict__ wqT, u16* __restrict__ vbT) {
  const int b = blockIdx.z, h = blockIdx.y, n0 = blockIdx.x * 256;
  const int tid = threadIdx.x, lane = tid & 63, wv = tid >> 6;
  const int lrow = lane & 15, lk = lane >> 4;
  const u16* Cb = ctx + (size_t)(b*16 + h) * 4096;
  floatx4 acc[4][4] = {};
  #pragma unroll
  for (int kk = 0; kk < 64; kk += 32) {
    short8 af[4], bff[4];
    #pragma unroll
    for (int m=0;m<4;m++) af[m]  = *(const short8*)(Cb + (m*16 + lrow)*64 + kk + lk*8);
    #pragma unroll
    for (int n=0;n<4;n++) bff[n] = *(const short8*)(wqT + (size_t)(n0 + wv*64 + n*16 + lrow)*1024 + h*64 + kk + lk*8);
    #pragma unroll
    for (int m=0;m<4;m++)
      #pragma unroll
      for (int n=0;n<4;n++)
        acc[m][n] = MFMA(af[m], bff[n], acc[m][n]);
  }
  u16* dst = vbT + (size_t)b * 1048576;
  #pragma unroll
  for (int m=0;m<4;m++)
    #pragma unroll
    for (int n=0;n<4;n++)
      #pragma unroll
      for (int r=0;r<4;r++) {
        int c = n0 + wv*64 + n*16 + lrow;
        int dd = m*16 + lk*4 + r;
        dst[(size_t)c*1024 + h*64 + dd] = f2bf(acc[m][n][r]);
      }
}

extern "C" void kernel_launch(void* const* d_in, const int* in_sizes, int n_in,
                              void* d_out, int out_size, void* d_ws, size_t ws_size,
                              hipStream_t stream) {
  const float* x     = (const float*)d_in[0];
  const int*   masks = (const int*)d_in[1];
  const float* w_qkv = (const float*)d_in[2];
  const float* w_out = (const float*)d_in[3];
  const float* b_out = (const float*)d_in[4];
  float* out = (float*)d_out;

  // Workspace layout (~105 MB):
  char* ws = (char*)d_ws;
  u16* xm  = (u16*)(ws);                    // 64 MB  [32768][1024]
  u16* wkv = (u16*)(ws + (64ull<<20));      // 4 MB   [2048][1024] (k,v rows of w_qkv)
  u16* wqT = (u16*)(ws + (68ull<<20));      // 2 MB   [1024 c][1024 e], scaled
  u16* wob = (u16*)(ws + (70ull<<20));      // 2 MB   [1024][1024]
  u16* ctx = (u16*)(ws + (72ull<<20));      // 1 MB   [128][64][64]
  u16* vbT = (u16*)(ws + (73ull<<20));      // 16 MB  [8][1024 c][1024 c']
  u16* mb  = (u16*)(ws + (89ull<<20));      // 16 MB  [8][1024 o][1024 c]

  // k/v live inside d_out (128 MiB of the 134.2 MB fp32 output buffer);
  // both dead before gemm_bt<1> overwrites d_out with the final result.
  u16* kbf = (u16*)d_out;                   // [8][1024][4096] bf16
  u16* vv  = (u16*)d_out + 33554432ull;     // [8][1024][4096] bf16

  k_maskcvt<<<16384, 256, 0, stream>>>(x, masks, xm);
  k_cvt<<<1024, 256, 0, stream>>>(w_qkv + 1048576, wkv);   // rows 1024..3071
  k_cvt<<<512, 256, 0, stream>>>(w_out, wob);
  k_cvtT<<<dim3(32,32), 256, 0, stream>>>(w_qkv, wqT);     // q rows, transposed+scaled

  gemm_bt<0><<<4096, 256, 0, stream>>>(wkv, xm, kbf, vv, nullptr, nullptr, nullptr);
  k_softmax<<<8192, 256, 0, stream>>>(kbf, masks);
  k_context<<<128, 256, 0, stream>>>(kbf, vv, ctx);
  k_vb<<<dim3(4,16,8), 256, 0, stream>>>(ctx, wqT, vbT);
  gemm_bt<2><<<dim3(64,1,8), 256, 0, stream>>>(wob, vbT, nullptr, nullptr, mb, nullptr, nullptr);
  gemm_bt<1><<<2048, 256, 0, stream>>>(xm, mb, nullptr, nullptr, nullptr, out, b_out);
}

// Round 5
// 548.630 us; speedup vs baseline: 1.3012x; 1.0342x over previous
//
#include <hip/hip_runtime.h>
#include <hip/hip_bf16.h>
#include <stdint.h>

typedef __attribute__((ext_vector_type(8))) short short8;
typedef __attribute__((ext_vector_type(4))) float floatx4;
typedef unsigned short u16;

#define MFMA(a,b,c) __builtin_amdgcn_mfma_f32_16x16x32_bf16(a,b,c,0,0,0)

__device__ __forceinline__ u16 f2bf(float f) {
  __hip_bfloat16 h = __float2bfloat16(f);
  return *reinterpret_cast<u16*>(&h);
}
__device__ __forceinline__ float bf2f(u16 u) {
  union { uint32_t i; float f; } v; v.i = ((uint32_t)u) << 16; return v.f;
}

__device__ __forceinline__ void gload16(const void* g, void* l) {
  __builtin_amdgcn_global_load_lds(
      (__attribute__((address_space(1))) void*)(uintptr_t)g,
      (__attribute__((address_space(3))) void*)l, 16, 0, 0);
}

// ---- convert + mask: xm[(b,l)][d] bf16, zeroed where masks[b,l] ----
__global__ void k_maskcvt(const float* __restrict__ x, const int* __restrict__ masks,
                          u16* __restrict__ xm) {
  int gid = blockIdx.x * blockDim.x + threadIdx.x;   // one per 8 elems
  size_t i8 = (size_t)gid * 8;
  int row = gid >> 7;                                // i8 / 1024
  int msk = masks[row];
  float4 v0 = make_float4(0.f,0.f,0.f,0.f), v1 = v0;
  if (!msk) {
    v0 = *(const float4*)(x + i8);
    v1 = *(const float4*)(x + i8 + 4);
  }
  ushort4 p0 = make_ushort4(f2bf(v0.x), f2bf(v0.y), f2bf(v0.z), f2bf(v0.w));
  ushort4 p1 = make_ushort4(f2bf(v1.x), f2bf(v1.y), f2bf(v1.z), f2bf(v1.w));
  *(ushort4*)(xm + i8) = p0;
  *(ushort4*)(xm + i8 + 4) = p1;
}

__global__ void k_cvt(const float* __restrict__ s, u16* __restrict__ d) {
  int gid = blockIdx.x * blockDim.x + threadIdx.x;
  size_t i8 = (size_t)gid * 8;
  float4 v0 = *(const float4*)(s + i8);
  float4 v1 = *(const float4*)(s + i8 + 4);
  ushort4 p0 = make_ushort4(f2bf(v0.x), f2bf(v0.y), f2bf(v0.z), f2bf(v0.w));
  ushort4 p1 = make_ushort4(f2bf(v1.x), f2bf(v1.y), f2bf(v1.z), f2bf(v1.w));
  *(ushort4*)(d + i8) = p0;
  *(ushort4*)(d + i8 + 4) = p1;
}

// ---- transpose+scale the q rows of w_qkv: wqT[c][e] = w_qkv[e][c] * 0.125 ----
__global__ __launch_bounds__(256) void k_cvtT(const float* __restrict__ src,
                                              u16* __restrict__ dst) {
  __shared__ float t[32][33];
  const int e0 = blockIdx.x * 32, c0 = blockIdx.y * 32;
  const int tx = threadIdx.x & 31, ty = threadIdx.x >> 5;   // ty in [0,8)
  #pragma unroll
  for (int i = 0; i < 4; i++)
    t[ty + i*8][tx] = src[(size_t)(e0 + ty + i*8) * 1024 + c0 + tx];
  __syncthreads();
  #pragma unroll
  for (int i = 0; i < 4; i++)
    dst[(size_t)(c0 + ty + i*8) * 1024 + e0 + tx] = f2bf(t[tx][ty + i*8] * 0.125f);
}

// ==== 256x256xBK64 8-wave pipelined BT-GEMM (T2+T3+T4+T5) ====
// MODE 0: A=wkv (2048x1024), B=xm (32768x1024) -> k/v bf16 (grid 1024, XCD-chunked)
// MODE 1: A=xm (32768x1024), B=mb[b] (1024x1024) -> out fp32 + bias (grid 512, XCD-chunked)
// LDS: double-buffered A,B tiles 256x64 bf16, XOR-swizzled (slot s^(row&7)) via
// pre-swizzled global source + same-swizzle ds_read (rule #21).
template<int MODE>
__global__ __launch_bounds__(512) void gemm256(
    const u16* __restrict__ A, const u16* __restrict__ Bm,
    u16* __restrict__ o_k, u16* __restrict__ o_v,
    float* __restrict__ outp, const float* __restrict__ bias) {
  constexpr int K = 1024, NT = 16;          // NT = K/64
  __shared__ u16 As[2][16384];              // 2 x 256rows x 64cols
  __shared__ u16 Bs[2][16384];
  const int tid = threadIdx.x, lane = tid & 63, w = tid >> 6;
  const int wr = w >> 2, wc = w & 3;        // 2x4 wave grid, 128x64 per wave
  const int lrow = lane & 15, lk = lane >> 4;

  int m_idx, n_idx;
  if (MODE == 0) { int id = blockIdx.x, j = id >> 3; m_idx = j & 7;  n_idx = (id & 7) * 16 + (j >> 3); }
  else           { int id = blockIdx.x, j = id >> 3; n_idx = j & 3;  m_idx = (id & 7) * 16 + (j >> 2); }
  const int m0 = m_idx * 256, n0 = n_idx * 256;

  const u16* Ap = A + (size_t)m0 * K;
  const u16* Bp = (MODE == 1) ? Bm + (size_t)(m0 >> 12) * 1048576 + (size_t)n0 * K
                              : Bm + (size_t)n0 * K;

  floatx4 acc[8][4] = {};

  auto STAGE = [&](int buf, int t) {
    const int k0 = t * 64;
    #pragma unroll
    for (int i = 0; i < 4; i++) {
      int li = i * 512 + tid;
      int row = li >> 3, s = li & 7;
      int slot = s ^ (row & 7);
      gload16(Ap + (size_t)row * K + k0 + slot * 8,
              (char*)&As[buf][0] + (i * 512 + w * 64) * 16);
    }
    #pragma unroll
    for (int i = 0; i < 4; i++) {
      int li = i * 512 + tid;
      int row = li >> 3, s = li & 7;
      int slot = s ^ (row & 7);
      gload16(Bp + (size_t)row * K + k0 + slot * 8,
              (char*)&Bs[buf][0] + (i * 512 + w * 64) * 16);
    }
  };

  STAGE(0, 0);
  for (int t = 0; t < NT; ++t) {
    const int buf = t & 1;
    if (t + 1 < NT) {
      STAGE(buf ^ 1, t + 1);                       // 8 loads in flight past barrier
      asm volatile("s_waitcnt vmcnt(8)" ::: "memory");   // own tile-t loads landed
    } else {
      asm volatile("s_waitcnt vmcnt(0)" ::: "memory");
    }
    __builtin_amdgcn_s_barrier();                  // everyone's tile-t loads landed
    asm volatile("" ::: "memory");
    const int swz = lrow & 7;
    #pragma unroll
    for (int ks = 0; ks < 2; ++ks) {
      short8 af[8], bf4[4];
      #pragma unroll
      for (int m = 0; m < 8; m++) {
        int r = wr * 128 + m * 16 + lrow;
        af[m] = *(const short8*)&As[buf][r * 64 + (((ks * 4 + lk) ^ swz) << 3)];
      }
      #pragma unroll
      for (int n = 0; n < 4; n++) {
        int r = wc * 64 + n * 16 + lrow;
        bf4[n] = *(const short8*)&Bs[buf][r * 64 + (((ks * 4 + lk) ^ swz) << 3)];
      }
      __builtin_amdgcn_s_setprio(1);
      #pragma unroll
      for (int m = 0; m < 8; m++)
        #pragma unroll
        for (int n = 0; n < 4; n++)
          acc[m][n] = MFMA(af[m], bf4[n], acc[m][n]);
      __builtin_amdgcn_s_setprio(0);
    }
    asm volatile("" ::: "memory");
    __builtin_amdgcn_s_barrier();                  // reads of buf done -> restageable
    asm volatile("" ::: "memory");
  }

  #pragma unroll
  for (int m = 0; m < 8; m++) {
    const int rbase = m0 + wr * 128 + m * 16;      // uniform per frag-row
    #pragma unroll
    for (int n = 0; n < 4; n++) {
      const int ocol = n0 + wc * 64 + n * 16 + lrow;
      floatx4 d = acc[m][n];
      if (MODE == 0) {
        const int b = ocol >> 12, l = ocol & 4095;
        if (rbase < 1024) {
          int orow = rbase + lk * 4;
          #pragma unroll
          for (int r = 0; r < 4; r++)
            o_k[((size_t)b * 1024 + orow + r) * 4096 + l] = f2bf(d[r]);
        } else {
          int orow = rbase - 1024 + lk * 4;
          #pragma unroll
          for (int r = 0; r < 4; r++)
            o_v[((size_t)b * 1024 + orow + r) * 4096 + l] = f2bf(d[r]);
        }
      } else {
        int orow = rbase + lk * 4;
        float bval = bias[ocol];
        #pragma unroll
        for (int r = 0; r < 4; r++)
          outp[(size_t)(orow + r) * 1024 + ocol] = d[r] + bval;
      }
    }
  }
}

// ---- old 128x128 BT-GEMM, kept for MODE 2 only (small per-batch GEMM) ----
// MODE 2: A=wout (1024x1024), B=vbT[b] (1024x1024): mb[b] bf16 (grid (64,1,8))
template<int MODE>
__global__ __launch_bounds__(256) void gemm_bt(
    const u16* __restrict__ A, const u16* __restrict__ Bm,
    u16* __restrict__ o_mb) {
  constexpr int K = 1024;
  __shared__ u16 As[128*32];
  __shared__ u16 Bs[128*32];
  const int tid = threadIdx.x;
  const int lane = tid & 63, w = tid >> 6;
  const int wr = w >> 1, wc = w & 1;
  const int lrow = lane & 15, lk = lane >> 4;

  const int m_idx = blockIdx.x & 7, n_idx = blockIdx.x >> 3, zb = blockIdx.z;
  const int m0 = m_idx * 128, n0 = n_idx * 128;

  const u16* Ap = A + (size_t)m0 * K;
  const u16* Bp = Bm + (size_t)zb * 1048576 + (size_t)n0 * K;

  floatx4 acc[4][4] = {};

  for (int k0 = 0; k0 < K; k0 += 32) {
    #pragma unroll
    for (int r = 0; r < 2; ++r) {
      int li = r*256 + tid;
      int row = li >> 2, seg = li & 3;
      gload16(Ap + (size_t)row * K + k0 + seg*8, (char*)As + (r*256 + w*64)*16);
      gload16(Bp + (size_t)row * K + k0 + seg*8, (char*)Bs + (r*256 + w*64)*16);
    }
    __syncthreads();
    short8 af[4], bff[4];
    #pragma unroll
    for (int m=0;m<4;m++) af[m]  = *(const short8*)&As[(wr*64 + m*16 + lrow)*32 + lk*8];
    #pragma unroll
    for (int n=0;n<4;n++) bff[n] = *(const short8*)&Bs[(wc*64 + n*16 + lrow)*32 + lk*8];
    #pragma unroll
    for (int m=0;m<4;m++)
      #pragma unroll
      for (int n=0;n<4;n++)
        acc[m][n] = MFMA(af[m], bff[n], acc[m][n]);
    __syncthreads();
  }

  #pragma unroll
  for (int m=0;m<4;m++) {
    const int rbase = m0 + wr*64 + m*16;
    #pragma unroll
    for (int n=0;n<4;n++) {
      const int ocol = n0 + wc*64 + n*16 + lrow;
      floatx4 d = acc[m][n];
      int orow = rbase + lk*4;
      #pragma unroll
      for (int r=0;r<4;r++)
        o_mb[(size_t)zb*1048576 + (size_t)(orow + r)*1024 + ocol] = f2bf(d[r]);
    }
  }
}

// ---- softmax over L per (b,row): kbf bf16 -> kbf bf16 IN-PLACE, masked -> 0 ----
__global__ __launch_bounds__(256) void k_softmax(u16* __restrict__ kbf,
    const int* __restrict__ masks) {
  const int row = blockIdx.x;            // 0..8191
  const int b = row >> 10;
  u16* src = kbf + (size_t)row * 4096;
  const int* mk = masks + (size_t)b * 4096;
  const int tid = threadIdx.x;
  const int lane = tid & 63, wv = tid >> 6;

  float v[16]; int mv[16];
  float mx = -INFINITY;
  #pragma unroll
  for (int i=0;i<4;i++) {
    int l = i*1024 + tid*4;
    ushort4 kv = *(const ushort4*)(src + l);
    int4 mm = *(const int4*)(mk + l);
    float f0=bf2f(kv.x), f1=bf2f(kv.y), f2=bf2f(kv.z), f3=bf2f(kv.w);
    v[i*4+0]=f0; v[i*4+1]=f1; v[i*4+2]=f2; v[i*4+3]=f3;
    mv[i*4+0]=mm.x; mv[i*4+1]=mm.y; mv[i*4+2]=mm.z; mv[i*4+3]=mm.w;
    if (!mm.x) mx = fmaxf(mx, f0);
    if (!mm.y) mx = fmaxf(mx, f1);
    if (!mm.z) mx = fmaxf(mx, f2);
    if (!mm.w) mx = fmaxf(mx, f3);
  }
  #pragma unroll
  for (int o=32;o;o>>=1) mx = fmaxf(mx, __shfl_xor(mx, o));
  __shared__ float sred[4];
  __shared__ float ssum[4];
  if (lane==0) sred[wv] = mx;
  __syncthreads();
  mx = fmaxf(fmaxf(sred[0],sred[1]), fmaxf(sred[2],sred[3]));

  float s = 0.f;
  #pragma unroll
  for (int i=0;i<16;i++) {
    float e = mv[i] ? 0.f : __expf(v[i]-mx);
    v[i] = e; s += e;
  }
  #pragma unroll
  for (int o=32;o;o>>=1) s += __shfl_xor(s, o);
  if (lane==0) ssum[wv] = s;
  __syncthreads();
  s = ssum[0]+ssum[1]+ssum[2]+ssum[3];
  float inv = 1.f/s;
  #pragma unroll
  for (int i=0;i<4;i++) {
    int l = i*1024 + tid*4;
    ushort4 p = make_ushort4(f2bf(v[i*4]*inv), f2bf(v[i*4+1]*inv),
                             f2bf(v[i*4+2]*inv), f2bf(v[i*4+3]*inv));
    *(ushort4*)(src + l) = p;
  }
}

// ---- context[bh][d][e] = sum_l ksm[bh*64+d][l] * vv[bh*64+e][l]; 4-wave K-split ----
__global__ __launch_bounds__(256) void k_context(const u16* __restrict__ ksm,
    const u16* __restrict__ vv, u16* __restrict__ ctx) {
  const int bh = blockIdx.x;             // 0..127
  const int tid = threadIdx.x, lane = tid&63, w = tid>>6;
  const int lrow = lane&15, lk = lane>>4;
  const u16* Kb = ksm + (size_t)bh*64*4096;
  const u16* Vb = vv  + (size_t)bh*64*4096;
  floatx4 acc[4][4] = {};
  const int kbeg = w*1024;
  for (int kk=0; kk<1024; kk+=32) {
    short8 af[4], bff[4];
    #pragma unroll
    for (int m=0;m<4;m++) af[m]  = *(const short8*)(Kb + (size_t)(m*16+lrow)*4096 + kbeg+kk + lk*8);
    #pragma unroll
    for (int n=0;n<4;n++) bff[n] = *(const short8*)(Vb + (size_t)(n*16+lrow)*4096 + kbeg+kk + lk*8);
    #pragma unroll
    for (int m=0;m<4;m++)
      #pragma unroll
      for (int n=0;n<4;n++)
        acc[m][n] = MFMA(af[m], bff[n], acc[m][n]);
  }
  __shared__ float red[4][4096];
  #pragma unroll
  for (int m=0;m<4;m++)
    #pragma unroll
    for (int n=0;n<4;n++)
      #pragma unroll
      for (int r=0;r<4;r++) {
        int dd = m*16 + lk*4 + r, ee = n*16 + lrow;
        red[w][dd*64+ee] = acc[m][n][r];
      }
  __syncthreads();
  u16* cb = ctx + (size_t)bh*4096;
  #pragma unroll
  for (int i=0;i<16;i++) {
    int idx = i*256 + tid;
    cb[idx] = f2bf(red[0][idx]+red[1][idx]+red[2][idx]+red[3][idx]);
  }
}

// ---- vbT[b][c][h*64+d] = sum_e ctx[b,h,d,e] * wqT[c][h*64+e] ----
__global__ __launch_bounds__(256) void k_vb(const u16* __restrict__ ctx,
    const u16* __restrict__ wqT, u16* __restrict__ vbT) {
  const int b = blockIdx.z, h = blockIdx.y, n0 = blockIdx.x * 256;
  const int tid = threadIdx.x, lane = tid & 63, wv = tid >> 6;
  const int lrow = lane & 15, lk = lane >> 4;
  const u16* Cb = ctx + (size_t)(b*16 + h) * 4096;
  floatx4 acc[4][4] = {};
  #pragma unroll
  for (int kk = 0; kk < 64; kk += 32) {
    short8 af[4], bff[4];
    #pragma unroll
    for (int m=0;m<4;m++) af[m]  = *(const short8*)(Cb + (m*16 + lrow)*64 + kk + lk*8);
    #pragma unroll
    for (int n=0;n<4;n++) bff[n] = *(const short8*)(wqT + (size_t)(n0 + wv*64 + n*16 + lrow)*1024 + h*64 + kk + lk*8);
    #pragma unroll
    for (int m=0;m<4;m++)
      #pragma unroll
      for (int n=0;n<4;n++)
        acc[m][n] = MFMA(af[m], bff[n], acc[m][n]);
  }
  u16* dst = vbT + (size_t)b * 1048576;
  #pragma unroll
  for (int m=0;m<4;m++)
    #pragma unroll
    for (int n=0;n<4;n++)
      #pragma unroll
      for (int r=0;r<4;r++) {
        int c = n0 + wv*64 + n*16 + lrow;
        int dd = m*16 + lk*4 + r;
        dst[(size_t)c*1024 + h*64 + dd] = f2bf(acc[m][n][r]);
      }
}

extern "C" void kernel_launch(void* const* d_in, const int* in_sizes, int n_in,
                              void* d_out, int out_size, void* d_ws, size_t ws_size,
                              hipStream_t stream) {
  const float* x     = (const float*)d_in[0];
  const int*   masks = (const int*)d_in[1];
  const float* w_qkv = (const float*)d_in[2];
  const float* w_out = (const float*)d_in[3];
  const float* b_out = (const float*)d_in[4];
  float* out = (float*)d_out;

  // Workspace layout (~105 MB):
  char* ws = (char*)d_ws;
  u16* xm  = (u16*)(ws);                    // 64 MB  [32768][1024]
  u16* wkv = (u16*)(ws + (64ull<<20));      // 4 MB   [2048][1024] (k,v rows of w_qkv)
  u16* wqT = (u16*)(ws + (68ull<<20));      // 2 MB   [1024 c][1024 e], scaled
  u16* wob = (u16*)(ws + (70ull<<20));      // 2 MB   [1024][1024]
  u16* ctx = (u16*)(ws + (72ull<<20));      // 1 MB   [128][64][64]
  u16* vbT = (u16*)(ws + (73ull<<20));      // 16 MB  [8][1024 c][1024 c']
  u16* mb  = (u16*)(ws + (89ull<<20));      // 16 MB  [8][1024 o][1024 c]

  // k/v live inside d_out; both dead before gemm256<1> overwrites d_out.
  u16* kbf = (u16*)d_out;                   // [8][1024][4096] bf16
  u16* vv  = (u16*)d_out + 33554432ull;     // [8][1024][4096] bf16

  k_maskcvt<<<16384, 256, 0, stream>>>(x, masks, xm);
  k_cvt<<<1024, 256, 0, stream>>>(w_qkv + 1048576, wkv);   // rows 1024..3071
  k_cvt<<<512, 256, 0, stream>>>(w_out, wob);
  k_cvtT<<<dim3(32,32), 256, 0, stream>>>(w_qkv, wqT);     // q rows, transposed+scaled

  gemm256<0><<<1024, 512, 0, stream>>>(wkv, xm, kbf, vv, nullptr, nullptr);
  k_softmax<<<8192, 256, 0, stream>>>(kbf, masks);
  k_context<<<128, 256, 0, stream>>>(kbf, vv, ctx);
  k_vb<<<dim3(4,16,8), 256, 0, stream>>>(ctx, wqT, vbT);
  gemm_bt<2><<<dim3(64,1,8), 256, 0, stream>>>(wob, vbT, mb);
  gemm256<1><<<512, 512, 0, stream>>>(xm, mb, nullptr, nullptr, out, b_out);
}